// Round 8
// baseline (1085.096 us; speedup 1.0000x reference)
//
#include <hip/hip_runtime.h>

// VectorQuantizer: inputs [8,4096,64] f32, weight [8192,64] f32.
// Outputs concat: quantized_st [2097152] f32, loss [1] f32, indices [32768] f32.
//
// R12 = R9 (passing, 251.6us) + batched recheck. The constant ~143us tail
// across R2/R6/R9 was the RECHECK's codebook traffic (2 MB per flagged row;
// cnt ~2k at MARGIN 4e-4 -> ~4 GB L2 ~ 90-120us), not launch gaps (the R10/R11
// mega-kernel chased that theory and is abandoned: global_load_lds staging
// cannot be made coherent intra-launch across XCDs).
// New recheck: each block processes 16 flagged rows x one 4096-code slice,
// streaming the codebook ONCE per 16 rows (traffic /16). Distance math is
// bit-identical to the proven scan (ascending fmaf chain, (x2+wsq)-2s,
// strict-< ascending tie-break; cross-thread/slice combine via atomicMin on
// ordered u64 = exact np argmin tie-break). All other kernels verbatim R9.

typedef short bf16x8 __attribute__((ext_vector_type(8)));
typedef float f32x4  __attribute__((ext_vector_type(4)));

#define N_ROWS 32768
#define DIM 64
#define K_CODES 8192
#define KSPLIT 8
#define KCHUNK 1024
#define OUT_Q 0
#define OUT_LOSS 2097152
#define OUT_IDX 2097153
#define MARGIN 4e-4f
#define KEYMASK 0xFFFFFF80u
#define RB 16        // rows per recheck batch
#define RSLICE 2     // code slices in recheck

// ---- helpers ----
__device__ __forceinline__ unsigned f2u_ord(float f) {
    unsigned u = __float_as_uint(f);
    return (u & 0x80000000u) ? ~u : (u | 0x80000000u);
}
__device__ __forceinline__ unsigned short bf16_rne(float f) {
    unsigned u = __float_as_uint(f);
    u += 0x7fffu + ((u >> 16) & 1u);
    return (unsigned short)(u >> 16);
}
__device__ __forceinline__ float bf16_to_f(unsigned short h) {
    return __uint_as_float(((unsigned)h) << 16);
}

// numpy pairwise_sum over 64 squared elements (exact np emulation)
__device__ __forceinline__ float np_pairwise_sq64(const float* v) {
    float r[8];
#pragma unroll
    for (int j = 0; j < 8; j++) r[j] = __fmul_rn(v[j], v[j]);
#pragma unroll
    for (int i = 8; i < 64; i += 8) {
#pragma unroll
        for (int j = 0; j < 8; j++)
            r[j] = __fadd_rn(r[j], __fmul_rn(v[i + j], v[i + j]));
    }
    return __fadd_rn(__fadd_rn(__fadd_rn(r[0], r[1]), __fadd_rn(r[2], r[3])),
                     __fadd_rn(__fadd_rn(r[4], r[5]), __fadd_rn(r[6], r[7])));
}

// ---------------- kernel 0: prep (wsq + wsqb + packedW + zero-init) ----------
__global__ __launch_bounds__(256) void vq_prep(const float* __restrict__ weight,
                                               float* __restrict__ wsq,
                                               float* __restrict__ wsqb,
                                               int4* __restrict__ packedW,
                                               int* __restrict__ rcount,
                                               float* __restrict__ loss_out,
                                               int* __restrict__ sdone) {
    int tid = threadIdx.x;
    if (blockIdx.x == 0 && tid == 0) { *rcount = 0; *loss_out = 0.f; }
    sdone[blockIdx.x * 256 + tid] = 0;

    if (tid < 64) {
        int k = blockIdx.x * 64 + tid;
        float w[64];
        const float4* wp = (const float4*)(weight + (size_t)k * DIM);
#pragma unroll
        for (int i = 0; i < 16; i++) {
            float4 t = wp[i];
            w[4 * i] = t.x; w[4 * i + 1] = t.y; w[4 * i + 2] = t.z; w[4 * i + 3] = t.w;
        }
        float s = np_pairwise_sq64(w);
        wsq[k] = s;
        wsqb[k] = s + 8.0f;   // BIAS folded for the MFMA accumulator init
    }

    int wave = tid >> 6;
    int lane = tid & 63;
    int tile = blockIdx.x * 4 + wave;     // 0..511
    int code = tile * 16 + (lane & 15);
    int kq = (lane >> 4) * 8;
    const float* wr = weight + (size_t)code * DIM;

    union { bf16x8 v; int4 q; } hi0, hi1, lo0, lo1;
#pragma unroll
    for (int j = 0; j < 8; j++) {
        float a = -2.0f * wr[kq + j];
        unsigned short ha = bf16_rne(a);
        hi0.v[j] = (short)ha;
        lo0.v[j] = (short)bf16_rne(a - bf16_to_f(ha));
        float b = -2.0f * wr[32 + kq + j];
        unsigned short hb = bf16_rne(b);
        hi1.v[j] = (short)hb;
        lo1.v[j] = (short)bf16_rne(b - bf16_to_f(hb));
    }
    size_t base = (size_t)tile * 4 * 64;
    packedW[base + 0 * 64 + lane] = hi0.q;
    packedW[base + 1 * 64 + lane] = hi1.q;
    packedW[base + 2 * 64 + lane] = lo0.q;
    packedW[base + 3 * 64 + lane] = lo1.q;
}

// ---------------- kernel 1: MFMA argmin top-2 over a 1024-code chunk ----------
// grid (256, KSPLIT=8) x 256. Block: 128 rows; wave: 32 rows (2 row-tiles).
__global__ __launch_bounds__(256) void vq_argmin_mfma(const float* __restrict__ inp,
                                                      const int4* __restrict__ packedW,
                                                      const float* __restrict__ wsqb,
                                                      unsigned long long* __restrict__ bestk,
                                                      unsigned* __restrict__ secd) {
    __shared__ int4 sB[1024];   // 16 KB: two 8 KB buffers (2 code-tiles each)
    int wave = threadIdx.x >> 6;
    int lane = threadIdx.x & 63;
    int rbase = blockIdx.x * 128 + wave * 32;
    int kbase = blockIdx.y * KCHUNK;

    int kq = (lane >> 4) * 8;
    bf16x8 ah[2][2], al[2][2];   // [row-tile][k-chunk]
#pragma unroll
    for (int rt = 0; rt < 2; rt++) {
        const float* xp = inp + (size_t)(rbase + rt * 16 + (lane & 15)) * DIM;
#pragma unroll
        for (int kc = 0; kc < 2; kc++) {
            const float* xq = xp + kc * 32 + kq;
#pragma unroll
            for (int j = 0; j < 8; j++) {
                float a = xq[j];
                unsigned short h = bf16_rne(a);
                ah[rt][kc][j] = (short)h;
                al[rt][kc][j] = (short)bf16_rne(a - bf16_to_f(h));
            }
        }
    }

    unsigned best[8], sec[8];
#pragma unroll
    for (int s = 0; s < 8; s++) { best[s] = 0xFFFFFFFFu; sec[s] = 0xFFFFFFFFu; }

#define STAGE(buf, g) do {                                                        \
        const char* _src = (const char*)packedW +                                 \
            ((size_t)(kbase >> 4) + (size_t)(g) * 2) * 4096 + wave * 2048;        \
        char* _dst = (char*)sB + (buf) * 8192 + wave * 2048;                      \
        _Pragma("unroll")                                                         \
        for (int _i = 0; _i < 2; _i++)                                            \
            __builtin_amdgcn_global_load_lds(                                     \
                (const __attribute__((address_space(1))) unsigned int*)(_src + _i * 1024 + lane * 16), \
                (__attribute__((address_space(3))) unsigned int*)(_dst + _i * 1024), \
                16, 0, 0);                                                        \
    } while (0)

    STAGE(0, 0);
    __syncthreads();   // drains vmcnt(0): buf0 ready

    for (int g = 0; g < 32; g++) {
        int buf = g & 1;
        if (g + 1 < 32) STAGE(buf ^ 1, g + 1);   // issue next-group loads FIRST
        int lane_code = kbase + g * 32 + (lane & 15);
#pragma unroll
        for (int t = 0; t < 2; t++) {
            const int4* bp = sB + buf * 512 + t * 256;
            union { int4 q; bf16x8 v; } bh0, bh1, bl0, bl1;
            bh0.q = bp[0 * 64 + lane];
            bh1.q = bp[1 * 64 + lane];
            bl0.q = bp[2 * 64 + lane];
            bl1.q = bp[3 * 64 + lane];
            float wq = wsqb[lane_code + t * 16];
            unsigned tid7 = (unsigned)(g * 2 + t);   // 0..63 tile id in chunk
#pragma unroll
            for (int rt = 0; rt < 2; rt++) {
                f32x4 acc = {wq, wq, wq, wq};   // c = wsq + 8 - 2*dot, directly
                acc = __builtin_amdgcn_mfma_f32_16x16x32_bf16(ah[rt][0], bh0.v, acc, 0, 0, 0);
                acc = __builtin_amdgcn_mfma_f32_16x16x32_bf16(ah[rt][1], bh1.v, acc, 0, 0, 0);
                acc = __builtin_amdgcn_mfma_f32_16x16x32_bf16(al[rt][0], bh0.v, acc, 0, 0, 0);
                acc = __builtin_amdgcn_mfma_f32_16x16x32_bf16(al[rt][1], bh1.v, acc, 0, 0, 0);
                acc = __builtin_amdgcn_mfma_f32_16x16x32_bf16(ah[rt][0], bl0.v, acc, 0, 0, 0);
                acc = __builtin_amdgcn_mfma_f32_16x16x32_bf16(ah[rt][1], bl1.v, acc, 0, 0, 0);
#pragma unroll
                for (int r = 0; r < 4; r++) {
                    unsigned key = (__float_as_uint(acc[r]) & KEYMASK) | tid7;
                    int s = rt * 4 + r;
                    unsigned mx = best[s] > key ? best[s] : key;
                    sec[s] = sec[s] < mx ? sec[s] : mx;
                    best[s] = best[s] < key ? best[s] : key;
                }
            }
        }
        __syncthreads();
    }
#undef STAGE

    unsigned col[8];
#pragma unroll
    for (int s = 0; s < 8; s++) col[s] = lane & 15;
#pragma unroll
    for (int m = 1; m < 16; m <<= 1) {
#pragma unroll
        for (int s = 0; s < 8; s++) {
            unsigned ok = (unsigned)__shfl_xor((int)best[s], m, 64);
            unsigned os = (unsigned)__shfl_xor((int)sec[s], m, 64);
            unsigned oc = (unsigned)__shfl_xor((int)col[s], m, 64);
            unsigned mx = best[s] > ok ? best[s] : ok;
            unsigned mn2 = sec[s] < os ? sec[s] : os;
            sec[s] = mn2 < mx ? mn2 : mx;
            bool take = ok < best[s];
            best[s] = take ? ok : best[s];
            col[s] = take ? oc : col[s];
        }
    }
    if ((lane & 15) == 0) {
        int g4 = lane >> 4;
#pragma unroll
        for (int rt = 0; rt < 2; rt++)
#pragma unroll
            for (int r = 0; r < 4; r++) {
                int row = rbase + rt * 16 + g4 * 4 + r;
                int s = rt * 4 + r;
                int code = kbase + (int)(best[s] & 127u) * 16 + (int)col[s];
                bestk[(size_t)blockIdx.y * N_ROWS + row] =
                    ((unsigned long long)best[s] << 32) | (unsigned)code;
                secd[(size_t)blockIdx.y * N_ROWS + row] = sec[s];
            }
    }
}

// ---------------- kernel 2: merge chunks, flag near-ties ----------------
__global__ __launch_bounds__(256) void vq_merge(const unsigned long long* __restrict__ bestk,
                                                const unsigned* __restrict__ secd,
                                                int* __restrict__ final_idx,
                                                int* __restrict__ recheck_rows,
                                                int* __restrict__ recheck_count,
                                                unsigned long long* __restrict__ rrk) {
    int row = blockIdx.x * 256 + threadIdx.x;

    unsigned long long ks[KSPLIT];
    unsigned ss[KSPLIT];
#pragma unroll
    for (int c = 0; c < KSPLIT; c++) {
        ks[c] = bestk[(size_t)c * N_ROWS + row];
        ss[c] = secd[(size_t)c * N_ROWS + row];
    }

    unsigned long long k1 = ks[0];
#pragma unroll
    for (int c = 1; c < KSPLIT; c++) k1 = (ks[c] < k1) ? ks[c] : k1;

    unsigned d2 = 0xFFFFFFFFu;
#pragma unroll
    for (int c = 0; c < KSPLIT; c++) {
        if (ks[c] != k1) {
            unsigned b = (unsigned)(ks[c] >> 32);
            d2 = b < d2 ? b : d2;
        }
        d2 = ss[c] < d2 ? ss[c] : d2;
    }

    final_idx[row] = (int)(k1 & 0xffffffffull);
    float f1 = __uint_as_float(((unsigned)(k1 >> 32)) & KEYMASK);
    float f2 = __uint_as_float(d2 & KEYMASK);
    if (f2 - f1 < MARGIN) {
        int slot = atomicAdd(recheck_count, 1);
        recheck_rows[slot] = row;
        rrk[slot] = 0xFFFFFFFFFFFFFFFFull;   // init combine key for this slot
    }
}

// ---------------- kernel 3: batched np-exact rescan of flagged rows ----------
// grid (256 batch-slots, RSLICE=2) x 256. Each block: RB=16 flagged rows x one
// 4096-code slice, codebook streamed ONCE per 16 rows (traffic /16 vs R9).
// Thread t: row t>>4, codes slice*4096 + (t&15) + 16j, split into 4 ascending
// chains for ILP. Strict-< ascending scan == np first-min tie-break; cross-
// thread/slice combine via atomicMin on u64 (ord(dist)<<32|idx). Publisher
// (sdone == RSLICE) writes final_idx plain (next dispatch reads it).
__global__ __launch_bounds__(256) void vq_recheck_np(const float* __restrict__ inp,
                                                     const float* __restrict__ weight,
                                                     const float* __restrict__ wsq,
                                                     const int* __restrict__ recheck_rows,
                                                     const int* __restrict__ recheck_count,
                                                     unsigned long long* __restrict__ rrk,
                                                     int* __restrict__ sdone,
                                                     int* __restrict__ final_idx) {
    __shared__ float xs[RB][DIM];
    __shared__ float x2s[RB];
    int tid = threadIdx.x;
    int slice = blockIdx.y;
    int cnt = *recheck_count;
    if (cnt > N_ROWS) cnt = N_ROWS;
    int nbatch = (cnt + RB - 1) / RB;

    for (int b = blockIdx.x; b < nbatch; b += gridDim.x) {
        int li0 = b * RB;
        int nr = cnt - li0; if (nr > RB) nr = RB;

        for (int e = tid; e < nr * DIM; e += 256) {
            int r = e >> 6;
            xs[r][e & 63] = inp[(size_t)recheck_rows[li0 + r] * DIM + (e & 63)];
        }
        __syncthreads();
        if (tid < nr) x2s[tid] = np_pairwise_sq64(xs[tid]);
        __syncthreads();

        int r = tid >> 4;
        if (r < nr) {
            float x2 = x2s[r];
            int cb = slice * (K_CODES / RSLICE) + (tid & 15);
            float bd[4];
            int bi[4];
#pragma unroll
            for (int k = 0; k < 4; k++) { bd[k] = 3.402823466e+38f; bi[k] = 0x7fffffff; }
            for (int j = 0; j < 64; j++) {
                int c0 = cb + j * 16;
                const float* w0 = weight + (size_t)c0 * DIM;
                const float* w1 = w0 + (size_t)1024 * DIM;
                const float* w2 = w1 + (size_t)1024 * DIM;
                const float* w3 = w2 + (size_t)1024 * DIM;
                float s0 = 0.f, s1 = 0.f, s2 = 0.f, s3 = 0.f;
#pragma unroll
                for (int i = 0; i < DIM; i++) {
                    float xv = xs[r][i];
                    s0 = __builtin_fmaf(xv, w0[i], s0);
                    s1 = __builtin_fmaf(xv, w1[i], s1);
                    s2 = __builtin_fmaf(xv, w2[i], s2);
                    s3 = __builtin_fmaf(xv, w3[i], s3);
                }
                float d0 = __fsub_rn(__fadd_rn(x2, wsq[c0]),        __fmul_rn(2.0f, s0));
                float d1 = __fsub_rn(__fadd_rn(x2, wsq[c0 + 1024]), __fmul_rn(2.0f, s1));
                float d2_ = __fsub_rn(__fadd_rn(x2, wsq[c0 + 2048]), __fmul_rn(2.0f, s2));
                float d3 = __fsub_rn(__fadd_rn(x2, wsq[c0 + 3072]), __fmul_rn(2.0f, s3));
                if (d0 < bd[0]) { bd[0] = d0; bi[0] = c0; }
                if (d1 < bd[1]) { bd[1] = d1; bi[1] = c0 + 1024; }
                if (d2_ < bd[2]) { bd[2] = d2_; bi[2] = c0 + 2048; }
                if (d3 < bd[3]) { bd[3] = d3; bi[3] = c0 + 3072; }
            }
            // combine chains in ascending-code order (strict < keeps smallest idx)
            float fb = bd[0]; int fi = bi[0];
#pragma unroll
            for (int k = 1; k < 4; k++)
                if (bd[k] < fb || (bd[k] == fb && bi[k] < fi)) { fb = bd[k]; fi = bi[k]; }
            unsigned long long key = ((unsigned long long)f2u_ord(fb) << 32) | (unsigned)fi;
            atomicMin(rrk + li0 + r, key);
        }
        __syncthreads();
        __threadfence();
        if (tid < nr) {
            int old = atomicAdd(&sdone[li0 + tid], 1);
            if (old == RSLICE - 1) {   // all slice-blocks for this li done
                unsigned long long w = atomicMin(rrk + li0 + tid, 0xFFFFFFFFFFFFFFFFull);
                final_idx[recheck_rows[li0 + tid]] = (int)(w & 0xffffffffull);
            }
        }
        __syncthreads();
    }
}

// ---------------- kernel 4: gather + STE + loss + index write ----------------
__global__ __launch_bounds__(256) void vq_final(const float* __restrict__ inp,
                                                const float* __restrict__ weight,
                                                const int* __restrict__ final_idx,
                                                float* __restrict__ out) {
    int gid = blockIdx.x * 256 + threadIdx.x;
    int row = gid >> 4;
    int sub = gid & 15;

    int idx = final_idx[row];

    float4 x = ((const float4*)inp)[gid];
    float4 w = ((const float4*)weight)[idx * 16 + sub];

    float4 q;
    q.x = x.x + (w.x - x.x);
    q.y = x.y + (w.y - x.y);
    q.z = x.z + (w.z - x.z);
    q.w = x.w + (w.w - x.w);
    ((float4*)(out + OUT_Q))[gid] = q;

    if (sub == 0) out[OUT_IDX + row] = (float)idx;

    float dx = w.x - x.x, dy = w.y - x.y, dz = w.z - x.z, dw = w.w - x.w;
    float lp = dx * dx + dy * dy + dz * dz + dw * dw;

#pragma unroll
    for (int o = 32; o > 0; o >>= 1) lp += __shfl_down(lp, o, 64);

    __shared__ float red[4];
    int wid = threadIdx.x >> 6;
    int lane = threadIdx.x & 63;
    if (lane == 0) red[wid] = lp;
    __syncthreads();
    if (threadIdx.x == 0) {
        float bs = red[0] + red[1] + red[2] + red[3];
        atomicAdd(out + OUT_LOSS, bs * (0.25f / 2097152.f));
    }
}

extern "C" void kernel_launch(void* const* d_in, const int* in_sizes, int n_in,
                              void* d_out, int out_size, void* d_ws, size_t ws_size,
                              hipStream_t stream) {
    const float* inp = (const float*)d_in[0];
    const float* weight = (const float*)d_in[1];
    float* out = (float*)d_out;

    char* p = (char*)d_ws;
    unsigned long long* bestk = (unsigned long long*)p; p += (size_t)KSPLIT * N_ROWS * 8; // 2 MB
    unsigned* secd  = (unsigned*)p;            p += (size_t)KSPLIT * N_ROWS * 4;          // 1 MB
    int* final_idx  = (int*)p;                 p += (size_t)N_ROWS * 4;                   // 128 KB
    int* rrows      = (int*)p;                 p += (size_t)N_ROWS * 4;                   // 128 KB
    int* rcount     = (int*)p;                 p += 256;                                  // 256 B
    float* wsq      = (float*)p;               p += (size_t)K_CODES * 4;                  // 32 KB
    float* wsqb     = (float*)p;               p += (size_t)K_CODES * 4;                  // 32 KB
    int4* packedW   = (int4*)p;                p += (size_t)512 * 4 * 64 * 16;            // 2 MB
    unsigned long long* rrk = (unsigned long long*)p; p += (size_t)N_ROWS * 8;            // 256 KB
    int* sdone      = (int*)p;                 p += (size_t)N_ROWS * 4;                   // 128 KB

    vq_prep<<<128, 256, 0, stream>>>(weight, wsq, wsqb, packedW, rcount,
                                     out + OUT_LOSS, sdone);
    vq_argmin_mfma<<<dim3(N_ROWS / 128, KSPLIT), 256, 0, stream>>>(
        inp, packedW, wsqb, bestk, secd);
    vq_merge<<<N_ROWS / 256, 256, 0, stream>>>(bestk, secd, final_idx, rrows, rcount, rrk);
    vq_recheck_np<<<dim3(256, RSLICE), 256, 0, stream>>>(inp, weight, wsq, rrows, rcount,
                                                         rrk, sdone, final_idx);
    vq_final<<<(N_ROWS * DIM / 4) / 256, 256, 0, stream>>>(inp, weight, final_idx, out);
}

// Round 9
// 347.089 us; speedup vs baseline: 3.1263x; 3.1263x over previous
//
#include <hip/hip_runtime.h>

// VectorQuantizer: inputs [8,4096,64] f32, weight [8192,64] f32.
// Outputs concat: quantized_st [2097152] f32, loss [1] f32, indices [32768] f32.
//
// R13 = R9 (passing, 251.6us) + register-batched recheck.
// R12 post-mortem: batching 16 rows/block cut codebook traffic but collapsed
// parallelism (250 blocks, 16k serial FMA+loads per thread) -> 900us, occ 0.9%.
// R13 keeps R9's (256 x 8-slice) grid and 4-codes-per-thread structure, but
// stages RB=8 flagged rows in LDS per batch and reuses each thread's weight
// row across all 8 rows via register accumulators s[8]:
//   - codebook L2 traffic /8  (~4 GB -> ~500 MB)
//   - per (row,code) distance = same exact ascending i=0..63 fmaf chain,
//     d = (x2 + wsq) - 2s; combine via u64 ordered key (ord(d)<<32|code):
//     min over ascending codes == strict-< scan == np first-min tie-break.
//   - per-row wave shuffle-reduce, lane0 atomicMin(rrk), proven sdone publish
//     (RSLICE=8 arrivals) writing final_idx for the next dispatch.
// All other kernels verbatim R9.

typedef short bf16x8 __attribute__((ext_vector_type(8)));
typedef float f32x4  __attribute__((ext_vector_type(4)));

#define N_ROWS 32768
#define DIM 64
#define K_CODES 8192
#define KSPLIT 8
#define KCHUNK 1024
#define OUT_Q 0
#define OUT_LOSS 2097152
#define OUT_IDX 2097153
#define MARGIN 4e-4f
#define KEYMASK 0xFFFFFF80u
#define RB 8         // rows per recheck batch (register accumulators)
#define RSLICE 8     // code slices in recheck (1024 codes each)

// ---- helpers ----
__device__ __forceinline__ unsigned f2u_ord(float f) {
    unsigned u = __float_as_uint(f);
    return (u & 0x80000000u) ? ~u : (u | 0x80000000u);
}
__device__ __forceinline__ unsigned short bf16_rne(float f) {
    unsigned u = __float_as_uint(f);
    u += 0x7fffu + ((u >> 16) & 1u);
    return (unsigned short)(u >> 16);
}
__device__ __forceinline__ float bf16_to_f(unsigned short h) {
    return __uint_as_float(((unsigned)h) << 16);
}

// numpy pairwise_sum over 64 squared elements (exact np emulation)
__device__ __forceinline__ float np_pairwise_sq64(const float* v) {
    float r[8];
#pragma unroll
    for (int j = 0; j < 8; j++) r[j] = __fmul_rn(v[j], v[j]);
#pragma unroll
    for (int i = 8; i < 64; i += 8) {
#pragma unroll
        for (int j = 0; j < 8; j++)
            r[j] = __fadd_rn(r[j], __fmul_rn(v[i + j], v[i + j]));
    }
    return __fadd_rn(__fadd_rn(__fadd_rn(r[0], r[1]), __fadd_rn(r[2], r[3])),
                     __fadd_rn(__fadd_rn(r[4], r[5]), __fadd_rn(r[6], r[7])));
}

// ---------------- kernel 0: prep (wsq + wsqb + packedW + zero-init) ----------
__global__ __launch_bounds__(256) void vq_prep(const float* __restrict__ weight,
                                               float* __restrict__ wsq,
                                               float* __restrict__ wsqb,
                                               int4* __restrict__ packedW,
                                               int* __restrict__ rcount,
                                               float* __restrict__ loss_out,
                                               int* __restrict__ sdone) {
    int tid = threadIdx.x;
    if (blockIdx.x == 0 && tid == 0) { *rcount = 0; *loss_out = 0.f; }
    sdone[blockIdx.x * 256 + tid] = 0;

    if (tid < 64) {
        int k = blockIdx.x * 64 + tid;
        float w[64];
        const float4* wp = (const float4*)(weight + (size_t)k * DIM);
#pragma unroll
        for (int i = 0; i < 16; i++) {
            float4 t = wp[i];
            w[4 * i] = t.x; w[4 * i + 1] = t.y; w[4 * i + 2] = t.z; w[4 * i + 3] = t.w;
        }
        float s = np_pairwise_sq64(w);
        wsq[k] = s;
        wsqb[k] = s + 8.0f;   // BIAS folded for the MFMA accumulator init
    }

    int wave = tid >> 6;
    int lane = tid & 63;
    int tile = blockIdx.x * 4 + wave;     // 0..511
    int code = tile * 16 + (lane & 15);
    int kq = (lane >> 4) * 8;
    const float* wr = weight + (size_t)code * DIM;

    union { bf16x8 v; int4 q; } hi0, hi1, lo0, lo1;
#pragma unroll
    for (int j = 0; j < 8; j++) {
        float a = -2.0f * wr[kq + j];
        unsigned short ha = bf16_rne(a);
        hi0.v[j] = (short)ha;
        lo0.v[j] = (short)bf16_rne(a - bf16_to_f(ha));
        float b = -2.0f * wr[32 + kq + j];
        unsigned short hb = bf16_rne(b);
        hi1.v[j] = (short)hb;
        lo1.v[j] = (short)bf16_rne(b - bf16_to_f(hb));
    }
    size_t base = (size_t)tile * 4 * 64;
    packedW[base + 0 * 64 + lane] = hi0.q;
    packedW[base + 1 * 64 + lane] = hi1.q;
    packedW[base + 2 * 64 + lane] = lo0.q;
    packedW[base + 3 * 64 + lane] = lo1.q;
}

// ---------------- kernel 1: MFMA argmin top-2 over a 1024-code chunk ----------
// grid (256, KSPLIT=8) x 256. Block: 128 rows; wave: 32 rows (2 row-tiles).
__global__ __launch_bounds__(256) void vq_argmin_mfma(const float* __restrict__ inp,
                                                      const int4* __restrict__ packedW,
                                                      const float* __restrict__ wsqb,
                                                      unsigned long long* __restrict__ bestk,
                                                      unsigned* __restrict__ secd) {
    __shared__ int4 sB[1024];   // 16 KB: two 8 KB buffers (2 code-tiles each)
    int wave = threadIdx.x >> 6;
    int lane = threadIdx.x & 63;
    int rbase = blockIdx.x * 128 + wave * 32;
    int kbase = blockIdx.y * KCHUNK;

    int kq = (lane >> 4) * 8;
    bf16x8 ah[2][2], al[2][2];   // [row-tile][k-chunk]
#pragma unroll
    for (int rt = 0; rt < 2; rt++) {
        const float* xp = inp + (size_t)(rbase + rt * 16 + (lane & 15)) * DIM;
#pragma unroll
        for (int kc = 0; kc < 2; kc++) {
            const float* xq = xp + kc * 32 + kq;
#pragma unroll
            for (int j = 0; j < 8; j++) {
                float a = xq[j];
                unsigned short h = bf16_rne(a);
                ah[rt][kc][j] = (short)h;
                al[rt][kc][j] = (short)bf16_rne(a - bf16_to_f(h));
            }
        }
    }

    unsigned best[8], sec[8];
#pragma unroll
    for (int s = 0; s < 8; s++) { best[s] = 0xFFFFFFFFu; sec[s] = 0xFFFFFFFFu; }

#define STAGE(buf, g) do {                                                        \
        const char* _src = (const char*)packedW +                                 \
            ((size_t)(kbase >> 4) + (size_t)(g) * 2) * 4096 + wave * 2048;        \
        char* _dst = (char*)sB + (buf) * 8192 + wave * 2048;                      \
        _Pragma("unroll")                                                         \
        for (int _i = 0; _i < 2; _i++)                                            \
            __builtin_amdgcn_global_load_lds(                                     \
                (const __attribute__((address_space(1))) unsigned int*)(_src + _i * 1024 + lane * 16), \
                (__attribute__((address_space(3))) unsigned int*)(_dst + _i * 1024), \
                16, 0, 0);                                                        \
    } while (0)

    STAGE(0, 0);
    __syncthreads();   // drains vmcnt(0): buf0 ready

    for (int g = 0; g < 32; g++) {
        int buf = g & 1;
        if (g + 1 < 32) STAGE(buf ^ 1, g + 1);   // issue next-group loads FIRST
        int lane_code = kbase + g * 32 + (lane & 15);
#pragma unroll
        for (int t = 0; t < 2; t++) {
            const int4* bp = sB + buf * 512 + t * 256;
            union { int4 q; bf16x8 v; } bh0, bh1, bl0, bl1;
            bh0.q = bp[0 * 64 + lane];
            bh1.q = bp[1 * 64 + lane];
            bl0.q = bp[2 * 64 + lane];
            bl1.q = bp[3 * 64 + lane];
            float wq = wsqb[lane_code + t * 16];
            unsigned tid7 = (unsigned)(g * 2 + t);   // 0..63 tile id in chunk
#pragma unroll
            for (int rt = 0; rt < 2; rt++) {
                f32x4 acc = {wq, wq, wq, wq};   // c = wsq + 8 - 2*dot, directly
                acc = __builtin_amdgcn_mfma_f32_16x16x32_bf16(ah[rt][0], bh0.v, acc, 0, 0, 0);
                acc = __builtin_amdgcn_mfma_f32_16x16x32_bf16(ah[rt][1], bh1.v, acc, 0, 0, 0);
                acc = __builtin_amdgcn_mfma_f32_16x16x32_bf16(al[rt][0], bh0.v, acc, 0, 0, 0);
                acc = __builtin_amdgcn_mfma_f32_16x16x32_bf16(al[rt][1], bh1.v, acc, 0, 0, 0);
                acc = __builtin_amdgcn_mfma_f32_16x16x32_bf16(ah[rt][0], bl0.v, acc, 0, 0, 0);
                acc = __builtin_amdgcn_mfma_f32_16x16x32_bf16(ah[rt][1], bl1.v, acc, 0, 0, 0);
#pragma unroll
                for (int r = 0; r < 4; r++) {
                    unsigned key = (__float_as_uint(acc[r]) & KEYMASK) | tid7;
                    int s = rt * 4 + r;
                    unsigned mx = best[s] > key ? best[s] : key;
                    sec[s] = sec[s] < mx ? sec[s] : mx;
                    best[s] = best[s] < key ? best[s] : key;
                }
            }
        }
        __syncthreads();
    }
#undef STAGE

    unsigned col[8];
#pragma unroll
    for (int s = 0; s < 8; s++) col[s] = lane & 15;
#pragma unroll
    for (int m = 1; m < 16; m <<= 1) {
#pragma unroll
        for (int s = 0; s < 8; s++) {
            unsigned ok = (unsigned)__shfl_xor((int)best[s], m, 64);
            unsigned os = (unsigned)__shfl_xor((int)sec[s], m, 64);
            unsigned oc = (unsigned)__shfl_xor((int)col[s], m, 64);
            unsigned mx = best[s] > ok ? best[s] : ok;
            unsigned mn2 = sec[s] < os ? sec[s] : os;
            sec[s] = mn2 < mx ? mn2 : mx;
            bool take = ok < best[s];
            best[s] = take ? ok : best[s];
            col[s] = take ? oc : col[s];
        }
    }
    if ((lane & 15) == 0) {
        int g4 = lane >> 4;
#pragma unroll
        for (int rt = 0; rt < 2; rt++)
#pragma unroll
            for (int r = 0; r < 4; r++) {
                int row = rbase + rt * 16 + g4 * 4 + r;
                int s = rt * 4 + r;
                int code = kbase + (int)(best[s] & 127u) * 16 + (int)col[s];
                bestk[(size_t)blockIdx.y * N_ROWS + row] =
                    ((unsigned long long)best[s] << 32) | (unsigned)code;
                secd[(size_t)blockIdx.y * N_ROWS + row] = sec[s];
            }
    }
}

// ---------------- kernel 2: merge chunks, flag near-ties ----------------
__global__ __launch_bounds__(256) void vq_merge(const unsigned long long* __restrict__ bestk,
                                                const unsigned* __restrict__ secd,
                                                int* __restrict__ final_idx,
                                                int* __restrict__ recheck_rows,
                                                int* __restrict__ recheck_count,
                                                unsigned long long* __restrict__ rrk) {
    int row = blockIdx.x * 256 + threadIdx.x;

    unsigned long long ks[KSPLIT];
    unsigned ss[KSPLIT];
#pragma unroll
    for (int c = 0; c < KSPLIT; c++) {
        ks[c] = bestk[(size_t)c * N_ROWS + row];
        ss[c] = secd[(size_t)c * N_ROWS + row];
    }

    unsigned long long k1 = ks[0];
#pragma unroll
    for (int c = 1; c < KSPLIT; c++) k1 = (ks[c] < k1) ? ks[c] : k1;

    unsigned d2 = 0xFFFFFFFFu;
#pragma unroll
    for (int c = 0; c < KSPLIT; c++) {
        if (ks[c] != k1) {
            unsigned b = (unsigned)(ks[c] >> 32);
            d2 = b < d2 ? b : d2;
        }
        d2 = ss[c] < d2 ? ss[c] : d2;
    }

    final_idx[row] = (int)(k1 & 0xffffffffull);
    float f1 = __uint_as_float(((unsigned)(k1 >> 32)) & KEYMASK);
    float f2 = __uint_as_float(d2 & KEYMASK);
    if (f2 - f1 < MARGIN) {
        int slot = atomicAdd(recheck_count, 1);
        recheck_rows[slot] = row;
        rrk[slot] = 0xFFFFFFFFFFFFFFFFull;   // init combine key for this slot
    }
}

// ---------------- kernel 3: batched np-exact rescan of flagged rows ----------
// grid (256, RSLICE=8) x 256. Per batch: RB=8 rows staged in LDS; each thread
// scans 4 ascending codes (slice*1024 + c*256 + tid), loading the weight row
// ONCE (float4) and accumulating all 8 rows in registers. Distance per
// (row,code) is the exact ascending i=0..63 fmaf chain, d=(x2+wsq)-2s, as in
// the proven R9 recheck. Combine: u64 key (ord(d)<<32|code) -> wave shuffle
// min -> lane0 atomicMin(rrk). 8th slice-arrival (sdone) publishes final_idx.
__global__ __launch_bounds__(256) void vq_recheck_np(const float* __restrict__ inp,
                                                     const float* __restrict__ weight,
                                                     const float* __restrict__ wsq,
                                                     const int* __restrict__ recheck_rows,
                                                     const int* __restrict__ recheck_count,
                                                     unsigned long long* __restrict__ rrk,
                                                     int* __restrict__ sdone,
                                                     int* __restrict__ final_idx) {
    __shared__ float xs[RB][DIM];
    __shared__ float x2s[RB];
    int tid = threadIdx.x;
    int lane = tid & 63;
    int slice = blockIdx.y;
    int cnt = *recheck_count;
    if (cnt > N_ROWS) cnt = N_ROWS;
    int nbatch = (cnt + RB - 1) / RB;

    for (int b = blockIdx.x; b < nbatch; b += gridDim.x) {
        int li0 = b * RB;
        int nr = cnt - li0; if (nr > RB) nr = RB;

        for (int e = tid; e < nr * DIM; e += 256) {
            int r = e >> 6;
            xs[r][e & 63] = inp[(size_t)recheck_rows[li0 + r] * DIM + (e & 63)];
        }
        __syncthreads();
        if (tid < nr) x2s[tid] = np_pairwise_sq64(xs[tid]);
        __syncthreads();

        unsigned long long bkey[RB];
#pragma unroll
        for (int r = 0; r < RB; r++) bkey[r] = 0xFFFFFFFFFFFFFFFFull;

#pragma unroll
        for (int c = 0; c < 4; c++) {
            int code = slice * (K_CODES / RSLICE) + c * 256 + tid;
            const float4* wp = (const float4*)(weight + (size_t)code * DIM);
            float s[RB];
#pragma unroll
            for (int r = 0; r < RB; r++) s[r] = 0.f;
#pragma unroll
            for (int i4 = 0; i4 < 16; i4++) {
                float4 w4 = wp[i4];
#pragma unroll
                for (int r = 0; r < RB; r++) {
                    float4 x4 = *(const float4*)(&xs[r][i4 * 4]);
                    s[r] = __builtin_fmaf(x4.x, w4.x, s[r]);
                    s[r] = __builtin_fmaf(x4.y, w4.y, s[r]);
                    s[r] = __builtin_fmaf(x4.z, w4.z, s[r]);
                    s[r] = __builtin_fmaf(x4.w, w4.w, s[r]);
                }
            }
            float wsqv = wsq[code];
#pragma unroll
            for (int r = 0; r < RB; r++) {
                float d = __fsub_rn(__fadd_rn(x2s[r], wsqv), __fmul_rn(2.0f, s[r]));
                unsigned long long key =
                    ((unsigned long long)f2u_ord(d) << 32) | (unsigned)code;
                bkey[r] = key < bkey[r] ? key : bkey[r];
            }
        }

        // per-row wave reduce (min of u64 key), lane0 -> global atomicMin
#pragma unroll
        for (int r = 0; r < RB; r++) {
            unsigned long long k = bkey[r];
#pragma unroll
            for (int m = 1; m < 64; m <<= 1) {
                unsigned hi = (unsigned)(k >> 32), lo = (unsigned)k;
                unsigned ohi = (unsigned)__shfl_xor((int)hi, m, 64);
                unsigned olo = (unsigned)__shfl_xor((int)lo, m, 64);
                unsigned long long o = ((unsigned long long)ohi << 32) | olo;
                k = o < k ? o : k;
            }
            if (lane == 0 && r < nr) atomicMin(rrk + li0 + r, k);
        }

        __syncthreads();
        __threadfence();
        if (tid < nr) {
            int old = atomicAdd(&sdone[li0 + tid], 1);
            if (old == RSLICE - 1) {   // all slice-blocks for this batch done
                unsigned long long w = atomicMin(rrk + li0 + tid, 0xFFFFFFFFFFFFFFFFull);
                final_idx[recheck_rows[li0 + tid]] = (int)(w & 0xffffffffull);
            }
        }
        __syncthreads();
    }
}

// ---------------- kernel 4: gather + STE + loss + index write ----------------
__global__ __launch_bounds__(256) void vq_final(const float* __restrict__ inp,
                                                const float* __restrict__ weight,
                                                const int* __restrict__ final_idx,
                                                float* __restrict__ out) {
    int gid = blockIdx.x * 256 + threadIdx.x;
    int row = gid >> 4;
    int sub = gid & 15;

    int idx = final_idx[row];

    float4 x = ((const float4*)inp)[gid];
    float4 w = ((const float4*)weight)[idx * 16 + sub];

    float4 q;
    q.x = x.x + (w.x - x.x);
    q.y = x.y + (w.y - x.y);
    q.z = x.z + (w.z - x.z);
    q.w = x.w + (w.w - x.w);
    ((float4*)(out + OUT_Q))[gid] = q;

    if (sub == 0) out[OUT_IDX + row] = (float)idx;

    float dx = w.x - x.x, dy = w.y - x.y, dz = w.z - x.z, dw = w.w - x.w;
    float lp = dx * dx + dy * dy + dz * dz + dw * dw;

#pragma unroll
    for (int o = 32; o > 0; o >>= 1) lp += __shfl_down(lp, o, 64);

    __shared__ float red[4];
    int wid = threadIdx.x >> 6;
    int lane = threadIdx.x & 63;
    if (lane == 0) red[wid] = lp;
    __syncthreads();
    if (threadIdx.x == 0) {
        float bs = red[0] + red[1] + red[2] + red[3];
        atomicAdd(out + OUT_LOSS, bs * (0.25f / 2097152.f));
    }
}

extern "C" void kernel_launch(void* const* d_in, const int* in_sizes, int n_in,
                              void* d_out, int out_size, void* d_ws, size_t ws_size,
                              hipStream_t stream) {
    const float* inp = (const float*)d_in[0];
    const float* weight = (const float*)d_in[1];
    float* out = (float*)d_out;

    char* p = (char*)d_ws;
    unsigned long long* bestk = (unsigned long long*)p; p += (size_t)KSPLIT * N_ROWS * 8; // 2 MB
    unsigned* secd  = (unsigned*)p;            p += (size_t)KSPLIT * N_ROWS * 4;          // 1 MB
    int* final_idx  = (int*)p;                 p += (size_t)N_ROWS * 4;                   // 128 KB
    int* rrows      = (int*)p;                 p += (size_t)N_ROWS * 4;                   // 128 KB
    int* rcount     = (int*)p;                 p += 256;                                  // 256 B
    float* wsq      = (float*)p;               p += (size_t)K_CODES * 4;                  // 32 KB
    float* wsqb     = (float*)p;               p += (size_t)K_CODES * 4;                  // 32 KB
    int4* packedW   = (int4*)p;                p += (size_t)512 * 4 * 64 * 16;            // 2 MB
    unsigned long long* rrk = (unsigned long long*)p; p += (size_t)N_ROWS * 8;            // 256 KB
    int* sdone      = (int*)p;                 p += (size_t)N_ROWS * 4;                   // 128 KB

    vq_prep<<<128, 256, 0, stream>>>(weight, wsq, wsqb, packedW, rcount,
                                     out + OUT_LOSS, sdone);
    vq_argmin_mfma<<<dim3(N_ROWS / 128, KSPLIT), 256, 0, stream>>>(
        inp, packedW, wsqb, bestk, secd);
    vq_merge<<<N_ROWS / 256, 256, 0, stream>>>(bestk, secd, final_idx, rrows, rcount, rrk);
    vq_recheck_np<<<dim3(256, RSLICE), 256, 0, stream>>>(inp, weight, wsq, rrows, rcount,
                                                         rrk, sdone, final_idx);
    vq_final<<<(N_ROWS * DIM / 4) / 256, 256, 0, stream>>>(inp, weight, final_idx, out);
}

// Round 10
// 241.022 us; speedup vs baseline: 4.5021x; 1.4401x over previous
//
#include <hip/hip_runtime.h>

// VectorQuantizer: inputs [8,4096,64] f32, weight [8192,64] f32.
// Outputs concat: quantized_st [2097152] f32, loss [1] f32, indices [32768] f32.
//
// R14 = R13 with the recheck spill removed. R13's recheck hit VGPR=256 +
// 65 MB scratch WRITE (spill): the fully-unrolled 4-code loop kept 4x(s[8] +
// load pipeline) live. Fix: serialize the code loop (#pragma unroll 1) ->
// one s[8] live at a time. Math/tie-break/publish identical to R13 (passed).
// Structure recap: recheck grid (256, RSLICE=8) x 256; RB=8 flagged rows
// staged in LDS; each thread scans 4 ascending codes serially, loading each
// weight row once (float4) and accumulating 8 rows in registers (codebook
// traffic /8 vs R9). Combine: u64 ordered key (ord(d)<<32|code) == np
// argmin tie-break; wave shuffle-min; lane0 atomicMin(rrk); 8th slice
// arrival (sdone) publishes final_idx. All other kernels verbatim R9.

typedef short bf16x8 __attribute__((ext_vector_type(8)));
typedef float f32x4  __attribute__((ext_vector_type(4)));

#define N_ROWS 32768
#define DIM 64
#define K_CODES 8192
#define KSPLIT 8
#define KCHUNK 1024
#define OUT_Q 0
#define OUT_LOSS 2097152
#define OUT_IDX 2097153
#define MARGIN 4e-4f
#define KEYMASK 0xFFFFFF80u
#define RB 8         // rows per recheck batch (register accumulators)
#define RSLICE 8     // code slices in recheck (1024 codes each)

// ---- helpers ----
__device__ __forceinline__ unsigned f2u_ord(float f) {
    unsigned u = __float_as_uint(f);
    return (u & 0x80000000u) ? ~u : (u | 0x80000000u);
}
__device__ __forceinline__ unsigned short bf16_rne(float f) {
    unsigned u = __float_as_uint(f);
    u += 0x7fffu + ((u >> 16) & 1u);
    return (unsigned short)(u >> 16);
}
__device__ __forceinline__ float bf16_to_f(unsigned short h) {
    return __uint_as_float(((unsigned)h) << 16);
}

// numpy pairwise_sum over 64 squared elements (exact np emulation)
__device__ __forceinline__ float np_pairwise_sq64(const float* v) {
    float r[8];
#pragma unroll
    for (int j = 0; j < 8; j++) r[j] = __fmul_rn(v[j], v[j]);
#pragma unroll
    for (int i = 8; i < 64; i += 8) {
#pragma unroll
        for (int j = 0; j < 8; j++)
            r[j] = __fadd_rn(r[j], __fmul_rn(v[i + j], v[i + j]));
    }
    return __fadd_rn(__fadd_rn(__fadd_rn(r[0], r[1]), __fadd_rn(r[2], r[3])),
                     __fadd_rn(__fadd_rn(r[4], r[5]), __fadd_rn(r[6], r[7])));
}

// ---------------- kernel 0: prep (wsq + wsqb + packedW + zero-init) ----------
__global__ __launch_bounds__(256) void vq_prep(const float* __restrict__ weight,
                                               float* __restrict__ wsq,
                                               float* __restrict__ wsqb,
                                               int4* __restrict__ packedW,
                                               int* __restrict__ rcount,
                                               float* __restrict__ loss_out,
                                               int* __restrict__ sdone) {
    int tid = threadIdx.x;
    if (blockIdx.x == 0 && tid == 0) { *rcount = 0; *loss_out = 0.f; }
    sdone[blockIdx.x * 256 + tid] = 0;

    if (tid < 64) {
        int k = blockIdx.x * 64 + tid;
        float w[64];
        const float4* wp = (const float4*)(weight + (size_t)k * DIM);
#pragma unroll
        for (int i = 0; i < 16; i++) {
            float4 t = wp[i];
            w[4 * i] = t.x; w[4 * i + 1] = t.y; w[4 * i + 2] = t.z; w[4 * i + 3] = t.w;
        }
        float s = np_pairwise_sq64(w);
        wsq[k] = s;
        wsqb[k] = s + 8.0f;   // BIAS folded for the MFMA accumulator init
    }

    int wave = tid >> 6;
    int lane = tid & 63;
    int tile = blockIdx.x * 4 + wave;     // 0..511
    int code = tile * 16 + (lane & 15);
    int kq = (lane >> 4) * 8;
    const float* wr = weight + (size_t)code * DIM;

    union { bf16x8 v; int4 q; } hi0, hi1, lo0, lo1;
#pragma unroll
    for (int j = 0; j < 8; j++) {
        float a = -2.0f * wr[kq + j];
        unsigned short ha = bf16_rne(a);
        hi0.v[j] = (short)ha;
        lo0.v[j] = (short)bf16_rne(a - bf16_to_f(ha));
        float b = -2.0f * wr[32 + kq + j];
        unsigned short hb = bf16_rne(b);
        hi1.v[j] = (short)hb;
        lo1.v[j] = (short)bf16_rne(b - bf16_to_f(hb));
    }
    size_t base = (size_t)tile * 4 * 64;
    packedW[base + 0 * 64 + lane] = hi0.q;
    packedW[base + 1 * 64 + lane] = hi1.q;
    packedW[base + 2 * 64 + lane] = lo0.q;
    packedW[base + 3 * 64 + lane] = lo1.q;
}

// ---------------- kernel 1: MFMA argmin top-2 over a 1024-code chunk ----------
// grid (256, KSPLIT=8) x 256. Block: 128 rows; wave: 32 rows (2 row-tiles).
__global__ __launch_bounds__(256) void vq_argmin_mfma(const float* __restrict__ inp,
                                                      const int4* __restrict__ packedW,
                                                      const float* __restrict__ wsqb,
                                                      unsigned long long* __restrict__ bestk,
                                                      unsigned* __restrict__ secd) {
    __shared__ int4 sB[1024];   // 16 KB: two 8 KB buffers (2 code-tiles each)
    int wave = threadIdx.x >> 6;
    int lane = threadIdx.x & 63;
    int rbase = blockIdx.x * 128 + wave * 32;
    int kbase = blockIdx.y * KCHUNK;

    int kq = (lane >> 4) * 8;
    bf16x8 ah[2][2], al[2][2];   // [row-tile][k-chunk]
#pragma unroll
    for (int rt = 0; rt < 2; rt++) {
        const float* xp = inp + (size_t)(rbase + rt * 16 + (lane & 15)) * DIM;
#pragma unroll
        for (int kc = 0; kc < 2; kc++) {
            const float* xq = xp + kc * 32 + kq;
#pragma unroll
            for (int j = 0; j < 8; j++) {
                float a = xq[j];
                unsigned short h = bf16_rne(a);
                ah[rt][kc][j] = (short)h;
                al[rt][kc][j] = (short)bf16_rne(a - bf16_to_f(h));
            }
        }
    }

    unsigned best[8], sec[8];
#pragma unroll
    for (int s = 0; s < 8; s++) { best[s] = 0xFFFFFFFFu; sec[s] = 0xFFFFFFFFu; }

#define STAGE(buf, g) do {                                                        \
        const char* _src = (const char*)packedW +                                 \
            ((size_t)(kbase >> 4) + (size_t)(g) * 2) * 4096 + wave * 2048;        \
        char* _dst = (char*)sB + (buf) * 8192 + wave * 2048;                      \
        _Pragma("unroll")                                                         \
        for (int _i = 0; _i < 2; _i++)                                            \
            __builtin_amdgcn_global_load_lds(                                     \
                (const __attribute__((address_space(1))) unsigned int*)(_src + _i * 1024 + lane * 16), \
                (__attribute__((address_space(3))) unsigned int*)(_dst + _i * 1024), \
                16, 0, 0);                                                        \
    } while (0)

    STAGE(0, 0);
    __syncthreads();   // drains vmcnt(0): buf0 ready

    for (int g = 0; g < 32; g++) {
        int buf = g & 1;
        if (g + 1 < 32) STAGE(buf ^ 1, g + 1);   // issue next-group loads FIRST
        int lane_code = kbase + g * 32 + (lane & 15);
#pragma unroll
        for (int t = 0; t < 2; t++) {
            const int4* bp = sB + buf * 512 + t * 256;
            union { int4 q; bf16x8 v; } bh0, bh1, bl0, bl1;
            bh0.q = bp[0 * 64 + lane];
            bh1.q = bp[1 * 64 + lane];
            bl0.q = bp[2 * 64 + lane];
            bl1.q = bp[3 * 64 + lane];
            float wq = wsqb[lane_code + t * 16];
            unsigned tid7 = (unsigned)(g * 2 + t);   // 0..63 tile id in chunk
#pragma unroll
            for (int rt = 0; rt < 2; rt++) {
                f32x4 acc = {wq, wq, wq, wq};   // c = wsq + 8 - 2*dot, directly
                acc = __builtin_amdgcn_mfma_f32_16x16x32_bf16(ah[rt][0], bh0.v, acc, 0, 0, 0);
                acc = __builtin_amdgcn_mfma_f32_16x16x32_bf16(ah[rt][1], bh1.v, acc, 0, 0, 0);
                acc = __builtin_amdgcn_mfma_f32_16x16x32_bf16(al[rt][0], bh0.v, acc, 0, 0, 0);
                acc = __builtin_amdgcn_mfma_f32_16x16x32_bf16(al[rt][1], bh1.v, acc, 0, 0, 0);
                acc = __builtin_amdgcn_mfma_f32_16x16x32_bf16(ah[rt][0], bl0.v, acc, 0, 0, 0);
                acc = __builtin_amdgcn_mfma_f32_16x16x32_bf16(ah[rt][1], bl1.v, acc, 0, 0, 0);
#pragma unroll
                for (int r = 0; r < 4; r++) {
                    unsigned key = (__float_as_uint(acc[r]) & KEYMASK) | tid7;
                    int s = rt * 4 + r;
                    unsigned mx = best[s] > key ? best[s] : key;
                    sec[s] = sec[s] < mx ? sec[s] : mx;
                    best[s] = best[s] < key ? best[s] : key;
                }
            }
        }
        __syncthreads();
    }
#undef STAGE

    unsigned col[8];
#pragma unroll
    for (int s = 0; s < 8; s++) col[s] = lane & 15;
#pragma unroll
    for (int m = 1; m < 16; m <<= 1) {
#pragma unroll
        for (int s = 0; s < 8; s++) {
            unsigned ok = (unsigned)__shfl_xor((int)best[s], m, 64);
            unsigned os = (unsigned)__shfl_xor((int)sec[s], m, 64);
            unsigned oc = (unsigned)__shfl_xor((int)col[s], m, 64);
            unsigned mx = best[s] > ok ? best[s] : ok;
            unsigned mn2 = sec[s] < os ? sec[s] : os;
            sec[s] = mn2 < mx ? mn2 : mx;
            bool take = ok < best[s];
            best[s] = take ? ok : best[s];
            col[s] = take ? oc : col[s];
        }
    }
    if ((lane & 15) == 0) {
        int g4 = lane >> 4;
#pragma unroll
        for (int rt = 0; rt < 2; rt++)
#pragma unroll
            for (int r = 0; r < 4; r++) {
                int row = rbase + rt * 16 + g4 * 4 + r;
                int s = rt * 4 + r;
                int code = kbase + (int)(best[s] & 127u) * 16 + (int)col[s];
                bestk[(size_t)blockIdx.y * N_ROWS + row] =
                    ((unsigned long long)best[s] << 32) | (unsigned)code;
                secd[(size_t)blockIdx.y * N_ROWS + row] = sec[s];
            }
    }
}

// ---------------- kernel 2: merge chunks, flag near-ties ----------------
__global__ __launch_bounds__(256) void vq_merge(const unsigned long long* __restrict__ bestk,
                                                const unsigned* __restrict__ secd,
                                                int* __restrict__ final_idx,
                                                int* __restrict__ recheck_rows,
                                                int* __restrict__ recheck_count,
                                                unsigned long long* __restrict__ rrk) {
    int row = blockIdx.x * 256 + threadIdx.x;

    unsigned long long ks[KSPLIT];
    unsigned ss[KSPLIT];
#pragma unroll
    for (int c = 0; c < KSPLIT; c++) {
        ks[c] = bestk[(size_t)c * N_ROWS + row];
        ss[c] = secd[(size_t)c * N_ROWS + row];
    }

    unsigned long long k1 = ks[0];
#pragma unroll
    for (int c = 1; c < KSPLIT; c++) k1 = (ks[c] < k1) ? ks[c] : k1;

    unsigned d2 = 0xFFFFFFFFu;
#pragma unroll
    for (int c = 0; c < KSPLIT; c++) {
        if (ks[c] != k1) {
            unsigned b = (unsigned)(ks[c] >> 32);
            d2 = b < d2 ? b : d2;
        }
        d2 = ss[c] < d2 ? ss[c] : d2;
    }

    final_idx[row] = (int)(k1 & 0xffffffffull);
    float f1 = __uint_as_float(((unsigned)(k1 >> 32)) & KEYMASK);
    float f2 = __uint_as_float(d2 & KEYMASK);
    if (f2 - f1 < MARGIN) {
        int slot = atomicAdd(recheck_count, 1);
        recheck_rows[slot] = row;
        rrk[slot] = 0xFFFFFFFFFFFFFFFFull;   // init combine key for this slot
    }
}

// ---------------- kernel 3: batched np-exact rescan of flagged rows ----------
// grid (256, RSLICE=8) x 256. Per batch: RB=8 rows staged in LDS; each thread
// scans 4 ascending codes SERIALLY (unroll 1 -> no spill; R13's full unroll
// hit VGPR=256 + 65 MB scratch), loading each weight row once (float4) and
// accumulating all 8 rows in registers. d=(x2+wsq)-2s with the exact ascending
// i=0..63 fmaf chain. Combine: u64 key (ord(d)<<32|code) -> wave shuffle min
// -> lane0 atomicMin(rrk); 8th slice-arrival (sdone) publishes final_idx.
__global__ __launch_bounds__(256) void vq_recheck_np(const float* __restrict__ inp,
                                                     const float* __restrict__ weight,
                                                     const float* __restrict__ wsq,
                                                     const int* __restrict__ recheck_rows,
                                                     const int* __restrict__ recheck_count,
                                                     unsigned long long* __restrict__ rrk,
                                                     int* __restrict__ sdone,
                                                     int* __restrict__ final_idx) {
    __shared__ float xs[RB][DIM];
    __shared__ float x2s[RB];
    int tid = threadIdx.x;
    int lane = tid & 63;
    int slice = blockIdx.y;
    int cnt = *recheck_count;
    if (cnt > N_ROWS) cnt = N_ROWS;
    int nbatch = (cnt + RB - 1) / RB;

    for (int b = blockIdx.x; b < nbatch; b += gridDim.x) {
        int li0 = b * RB;
        int nr = cnt - li0; if (nr > RB) nr = RB;

        for (int e = tid; e < nr * DIM; e += 256) {
            int r = e >> 6;
            xs[r][e & 63] = inp[(size_t)recheck_rows[li0 + r] * DIM + (e & 63)];
        }
        __syncthreads();
        if (tid < nr) x2s[tid] = np_pairwise_sq64(xs[tid]);
        __syncthreads();

        unsigned long long bkey[RB];
#pragma unroll
        for (int r = 0; r < RB; r++) bkey[r] = 0xFFFFFFFFFFFFFFFFull;

#pragma unroll 1   // SERIAL: full unroll spilled (VGPR 256, 65 MB scratch)
        for (int c = 0; c < 4; c++) {
            int code = slice * (K_CODES / RSLICE) + c * 256 + tid;
            const float4* wp = (const float4*)(weight + (size_t)code * DIM);
            float s[RB];
#pragma unroll
            for (int r = 0; r < RB; r++) s[r] = 0.f;
#pragma unroll
            for (int i4 = 0; i4 < 16; i4++) {
                float4 w4 = wp[i4];
#pragma unroll
                for (int r = 0; r < RB; r++) {
                    float4 x4 = *(const float4*)(&xs[r][i4 * 4]);
                    s[r] = __builtin_fmaf(x4.x, w4.x, s[r]);
                    s[r] = __builtin_fmaf(x4.y, w4.y, s[r]);
                    s[r] = __builtin_fmaf(x4.z, w4.z, s[r]);
                    s[r] = __builtin_fmaf(x4.w, w4.w, s[r]);
                }
            }
            float wsqv = wsq[code];
#pragma unroll
            for (int r = 0; r < RB; r++) {
                float d = __fsub_rn(__fadd_rn(x2s[r], wsqv), __fmul_rn(2.0f, s[r]));
                unsigned long long key =
                    ((unsigned long long)f2u_ord(d) << 32) | (unsigned)code;
                bkey[r] = key < bkey[r] ? key : bkey[r];
            }
        }

        // per-row wave reduce (min of u64 key), lane0 -> global atomicMin
#pragma unroll 1
        for (int r = 0; r < RB; r++) {
            unsigned long long k = bkey[r];
#pragma unroll
            for (int m = 1; m < 64; m <<= 1) {
                unsigned hi = (unsigned)(k >> 32), lo = (unsigned)k;
                unsigned ohi = (unsigned)__shfl_xor((int)hi, m, 64);
                unsigned olo = (unsigned)__shfl_xor((int)lo, m, 64);
                unsigned long long o = ((unsigned long long)ohi << 32) | olo;
                k = o < k ? o : k;
            }
            if (lane == 0 && r < nr) atomicMin(rrk + li0 + r, k);
        }

        __syncthreads();
        __threadfence();
        if (tid < nr) {
            int old = atomicAdd(&sdone[li0 + tid], 1);
            if (old == RSLICE - 1) {   // all slice-blocks for this batch done
                unsigned long long w = atomicMin(rrk + li0 + tid, 0xFFFFFFFFFFFFFFFFull);
                final_idx[recheck_rows[li0 + tid]] = (int)(w & 0xffffffffull);
            }
        }
        __syncthreads();
    }
}

// ---------------- kernel 4: gather + STE + loss + index write ----------------
__global__ __launch_bounds__(256) void vq_final(const float* __restrict__ inp,
                                                const float* __restrict__ weight,
                                                const int* __restrict__ final_idx,
                                                float* __restrict__ out) {
    int gid = blockIdx.x * 256 + threadIdx.x;
    int row = gid >> 4;
    int sub = gid & 15;

    int idx = final_idx[row];

    float4 x = ((const float4*)inp)[gid];
    float4 w = ((const float4*)weight)[idx * 16 + sub];

    float4 q;
    q.x = x.x + (w.x - x.x);
    q.y = x.y + (w.y - x.y);
    q.z = x.z + (w.z - x.z);
    q.w = x.w + (w.w - x.w);
    ((float4*)(out + OUT_Q))[gid] = q;

    if (sub == 0) out[OUT_IDX + row] = (float)idx;

    float dx = w.x - x.x, dy = w.y - x.y, dz = w.z - x.z, dw = w.w - x.w;
    float lp = dx * dx + dy * dy + dz * dz + dw * dw;

#pragma unroll
    for (int o = 32; o > 0; o >>= 1) lp += __shfl_down(lp, o, 64);

    __shared__ float red[4];
    int wid = threadIdx.x >> 6;
    int lane = threadIdx.x & 63;
    if (lane == 0) red[wid] = lp;
    __syncthreads();
    if (threadIdx.x == 0) {
        float bs = red[0] + red[1] + red[2] + red[3];
        atomicAdd(out + OUT_LOSS, bs * (0.25f / 2097152.f));
    }
}

extern "C" void kernel_launch(void* const* d_in, const int* in_sizes, int n_in,
                              void* d_out, int out_size, void* d_ws, size_t ws_size,
                              hipStream_t stream) {
    const float* inp = (const float*)d_in[0];
    const float* weight = (const float*)d_in[1];
    float* out = (float*)d_out;

    char* p = (char*)d_ws;
    unsigned long long* bestk = (unsigned long long*)p; p += (size_t)KSPLIT * N_ROWS * 8; // 2 MB
    unsigned* secd  = (unsigned*)p;            p += (size_t)KSPLIT * N_ROWS * 4;          // 1 MB
    int* final_idx  = (int*)p;                 p += (size_t)N_ROWS * 4;                   // 128 KB
    int* rrows      = (int*)p;                 p += (size_t)N_ROWS * 4;                   // 128 KB
    int* rcount     = (int*)p;                 p += 256;                                  // 256 B
    float* wsq      = (float*)p;               p += (size_t)K_CODES * 4;                  // 32 KB
    float* wsqb     = (float*)p;               p += (size_t)K_CODES * 4;                  // 32 KB
    int4* packedW   = (int4*)p;                p += (size_t)512 * 4 * 64 * 16;            // 2 MB
    unsigned long long* rrk = (unsigned long long*)p; p += (size_t)N_ROWS * 8;            // 256 KB
    int* sdone      = (int*)p;                 p += (size_t)N_ROWS * 4;                   // 128 KB

    vq_prep<<<128, 256, 0, stream>>>(weight, wsq, wsqb, packedW, rcount,
                                     out + OUT_LOSS, sdone);
    vq_argmin_mfma<<<dim3(N_ROWS / 128, KSPLIT), 256, 0, stream>>>(
        inp, packedW, wsqb, bestk, secd);
    vq_merge<<<N_ROWS / 256, 256, 0, stream>>>(bestk, secd, final_idx, rrows, rcount, rrk);
    vq_recheck_np<<<dim3(256, RSLICE), 256, 0, stream>>>(inp, weight, wsq, rrows, rcount,
                                                         rrk, sdone, final_idx);
    vq_final<<<(N_ROWS * DIM / 4) / 256, 256, 0, stream>>>(inp, weight, final_idx, out);
}